// Round 1
// baseline (2395.694 us; speedup 1.0000x reference)
//
#include <hip/hip_runtime.h>

// SineLSTM: 2-layer LSTM (H=50), B=512 rows fully independent -> each block
// owns BT rows and runs the entire T+predict time loop internally.
// Weights live in per-thread VGPRs (thread j<200 holds gate-row j of
// W_hh1 / W_ih2 / W_hh2 = 150 floats), loaded once, reused for all 1056 steps.
// States h1/c1/h2/c2 + gates live in LDS; activation reads are wave-uniform
// (LDS broadcast, conflict-free).

#define Hh   50
#define G4   200      // 4*H
#define BT   2        // batch rows per block
#define TLEN 1024     // teacher-forced sequence length (setup_inputs fixed)

__device__ __forceinline__ float fast_sigmoid(float v) {
    return 1.0f / (1.0f + __expf(-v));
}
__device__ __forceinline__ float fast_tanh(float v) {
    // 1 - 2/(e^{2v}+1); saturates correctly for |v| large (exp->0 or inf)
    return 1.0f - 2.0f / (__expf(2.0f * v) + 1.0f);
}

extern "C" __global__ __launch_bounds__(256)
void sine_lstm_kernel(const float* __restrict__ x,
                      const float* __restrict__ W_ih1,
                      const float* __restrict__ W_hh1,
                      const float* __restrict__ b_ih1,
                      const float* __restrict__ b_hh1,
                      const float* __restrict__ W_ih2,
                      const float* __restrict__ W_hh2,
                      const float* __restrict__ b_ih2,
                      const float* __restrict__ b_hh2,
                      const float* __restrict__ W_lin,
                      const float* __restrict__ b_lin,
                      const int*   __restrict__ predict_p,
                      float* __restrict__ out,
                      int T)
{
    __shared__ float x_lds[BT][TLEN];
    __shared__ float h1[BT][Hh], c1[BT][Hh], h2[BT][Hh], c2[BT][Hh];
    __shared__ float gates[BT][G4];
    __shared__ float o_lds[BT];

    const int tid = threadIdx.x;
    const int b0  = blockIdx.x * BT;
    const int predict = *predict_p;
    const int S = T + predict;

    // ---- stage x rows into LDS (coalesced) ----
    for (int i = tid; i < BT * TLEN; i += 256) {
        int b = i >> 10;          // i / TLEN
        int t = i & (TLEN - 1);   // i % TLEN
        x_lds[b][t] = x[(size_t)(b0 + b) * T + t];
    }
    // ---- zero states ----
    if (tid < Hh) {
        #pragma unroll
        for (int b = 0; b < BT; ++b) {
            h1[b][tid] = 0.0f; c1[b][tid] = 0.0f;
            h2[b][tid] = 0.0f; c2[b][tid] = 0.0f;
        }
    }

    // ---- per-thread weight rows (VGPR-resident for the whole loop) ----
    const int j = tid;
    float w1[Hh], wi2[Hh], wh2[Hh];
    float wih1_j = 0.0f, b1_j = 0.0f, b2_j = 0.0f;
    if (j < G4) {
        wih1_j = W_ih1[j];
        b1_j = b_ih1[j] + b_hh1[j];
        b2_j = b_ih2[j] + b_hh2[j];
        #pragma unroll
        for (int k = 0; k < Hh; ++k) {
            w1[k]  = W_hh1[j * Hh + k];
            wi2[k] = W_ih2[j * Hh + k];
            wh2[k] = W_hh2[j * Hh + k];
        }
    }

    // update-phase mapping: wave id = row, lane = hidden unit
    const int ub  = tid >> 6;
    const int ujj = tid & 63;
    const float wlin_j = (ujj < Hh) ? W_lin[ujj] : 0.0f;
    const float blin   = b_lin[0];

    __syncthreads();

    for (int s = 0; s < S; ++s) {
        // ======== layer 1: gates1[b][j] = b1 + xin*W_ih1[j] + h1[b]·W_hh1[j] ========
        if (j < G4) {
            #pragma unroll
            for (int b = 0; b < BT; ++b) {
                float xin = (s < T) ? x_lds[b][s] : o_lds[b];
                float a0 = 0.0f, a1 = 0.0f, a2 = 0.0f, a3 = 0.0f;
                #pragma unroll
                for (int k = 0; k < 48; k += 4) {
                    a0 += w1[k]     * h1[b][k];
                    a1 += w1[k + 1] * h1[b][k + 1];
                    a2 += w1[k + 2] * h1[b][k + 2];
                    a3 += w1[k + 3] * h1[b][k + 3];
                }
                a0 += w1[48] * h1[b][48];
                a1 += w1[49] * h1[b][49];
                gates[b][j] = ((a0 + a2) + (a1 + a3)) + b1_j + xin * wih1_j;
            }
        }
        __syncthreads();

        // ======== layer 1 update: lane jj of wave b owns unit jj ========
        if (ub < BT && ujj < Hh) {
            float ig = gates[ub][ujj];
            float fg = gates[ub][ujj + Hh];
            float gg = gates[ub][ujj + 2 * Hh];
            float og = gates[ub][ujj + 3 * Hh];
            float c  = c1[ub][ujj];
            float cn = fast_sigmoid(fg) * c + fast_sigmoid(ig) * fast_tanh(gg);
            c1[ub][ujj] = cn;
            h1[ub][ujj] = fast_sigmoid(og) * fast_tanh(cn);
        }
        __syncthreads();

        // ======== layer 2: gates2[b][j] = b2 + h1[b]·W_ih2[j] + h2[b]·W_hh2[j] ========
        if (j < G4) {
            #pragma unroll
            for (int b = 0; b < BT; ++b) {
                float a0 = 0.0f, a1 = 0.0f, a2 = 0.0f, a3 = 0.0f;
                #pragma unroll
                for (int k = 0; k < 48; k += 4) {
                    a0 += wi2[k]     * h1[b][k];
                    a1 += wi2[k + 1] * h1[b][k + 1];
                    a2 += wi2[k + 2] * h1[b][k + 2];
                    a3 += wi2[k + 3] * h1[b][k + 3];
                }
                a0 += wi2[48] * h1[b][48];
                a1 += wi2[49] * h1[b][49];
                #pragma unroll
                for (int k = 0; k < 48; k += 4) {
                    a0 += wh2[k]     * h2[b][k];
                    a1 += wh2[k + 1] * h2[b][k + 1];
                    a2 += wh2[k + 2] * h2[b][k + 2];
                    a3 += wh2[k + 3] * h2[b][k + 3];
                }
                a0 += wh2[48] * h2[b][48];
                a1 += wh2[49] * h2[b][49];
                gates[b][j] = ((a0 + a2) + (a1 + a3)) + b2_j;
            }
        }
        __syncthreads();

        // ======== layer 2 update + output dot (wave shuffle reduce) ========
        float part = 0.0f;
        if (ub < BT && ujj < Hh) {
            float ig = gates[ub][ujj];
            float fg = gates[ub][ujj + Hh];
            float gg = gates[ub][ujj + 2 * Hh];
            float og = gates[ub][ujj + 3 * Hh];
            float c  = c2[ub][ujj];
            float cn = fast_sigmoid(fg) * c + fast_sigmoid(ig) * fast_tanh(gg);
            float hn = fast_sigmoid(og) * fast_tanh(cn);
            c2[ub][ujj] = cn;
            h2[ub][ujj] = hn;
            part = hn * wlin_j;
        }
        #pragma unroll
        for (int off = 32; off > 0; off >>= 1)
            part += __shfl_down(part, off);
        if (ub < BT && ujj == 0) {
            float o = part + blin;
            o_lds[ub] = o;
            out[(size_t)(b0 + ub) * S + s] = o;
        }
        __syncthreads();
    }
}

extern "C" void kernel_launch(void* const* d_in, const int* in_sizes, int n_in,
                              void* d_out, int out_size, void* d_ws, size_t ws_size,
                              hipStream_t stream) {
    const float* x      = (const float*)d_in[0];
    const float* W_ih1  = (const float*)d_in[1];
    const float* W_hh1  = (const float*)d_in[2];
    const float* b_ih1  = (const float*)d_in[3];
    const float* b_hh1  = (const float*)d_in[4];
    const float* W_ih2  = (const float*)d_in[5];
    const float* W_hh2  = (const float*)d_in[6];
    const float* b_ih2  = (const float*)d_in[7];
    const float* b_hh2  = (const float*)d_in[8];
    const float* W_lin  = (const float*)d_in[9];
    const float* b_lin  = (const float*)d_in[10];
    const int*   pred   = (const int*)d_in[11];
    float* out = (float*)d_out;

    const int B = 512;                 // fixed by setup_inputs
    const int T = in_sizes[0] / B;     // 1024

    dim3 grid(B / BT), block(256);
    hipLaunchKernelGGL(sine_lstm_kernel, grid, block, 0, stream,
                       x, W_ih1, W_hh1, b_ih1, b_hh1,
                       W_ih2, W_hh2, b_ih2, b_hh2,
                       W_lin, b_lin, pred, out, T);
}

// Round 2
// 1641.695 us; speedup vs baseline: 1.4593x; 1.4593x over previous
//
#include <hip/hip_runtime.h>

// SineLSTM: 2-layer LSTM (H=50), B=512 independent rows.
// R2: BT=1 row/block, grid=512 -> 2 blocks/CU co-resident (their serial
// phases overlap at barriers). __launch_bounds__(256,2) caps VGPRs at 256 so
// the 150 per-thread weight floats stay in architectural VGPRs (R1's default
// heuristic capped at 100 VGPRs and spilled weights to AGPRs -> accvgpr_read
// per FMA). 3 barriers/step (g1/g2 split buffers); layer-2 update split:
// wave0 = state update, wave1 = redundant activation + output dot/reduce.

#define Hh   50
#define G4   200      // 4*H
#define TLEN 1024     // teacher-forced sequence length (setup_inputs fixed)

__device__ __forceinline__ float fast_sigmoid(float v) {
    return 1.0f / (1.0f + __expf(-v));
}
__device__ __forceinline__ float fast_tanh(float v) {
    // 1 - 2/(e^{2v}+1); saturates correctly for |v| large
    return 1.0f - 2.0f / (__expf(2.0f * v) + 1.0f);
}

extern "C" __global__ __launch_bounds__(256, 2)
void sine_lstm_kernel(const float* __restrict__ x,
                      const float* __restrict__ W_ih1,
                      const float* __restrict__ W_hh1,
                      const float* __restrict__ b_ih1,
                      const float* __restrict__ b_hh1,
                      const float* __restrict__ W_ih2,
                      const float* __restrict__ W_hh2,
                      const float* __restrict__ b_ih2,
                      const float* __restrict__ b_hh2,
                      const float* __restrict__ W_lin,
                      const float* __restrict__ b_lin,
                      const int*   __restrict__ predict_p,
                      float* __restrict__ out,
                      int T)
{
    __shared__ __align__(16) float x_lds[TLEN];
    __shared__ __align__(16) float h1[64], c1v[64], h2[64], c2v[64];
    __shared__ __align__(16) float g1[G4], g2[G4];
    __shared__ float o_lds;

    const int tid = threadIdx.x;
    const int b   = blockIdx.x;            // one batch row per block
    const int predict = *predict_p;
    const int S = T + predict;

    // ---- stage x row into LDS (coalesced) ----
    for (int i = tid; i < TLEN; i += 256)
        x_lds[i] = x[(size_t)b * T + i];
    // ---- zero states ----
    if (tid < Hh) { h1[tid] = 0.0f; c1v[tid] = 0.0f; h2[tid] = 0.0f; c2v[tid] = 0.0f; }

    // ---- per-thread weight rows (VGPR-resident for the whole loop) ----
    const int j = tid;
    float w1[Hh], wi2[Hh], wh2[Hh];
    float wih1_j = 0.0f, b1_j = 0.0f, b2_j = 0.0f;
    if (j < G4) {
        wih1_j = W_ih1[j];
        b1_j = b_ih1[j] + b_hh1[j];
        b2_j = b_ih2[j] + b_hh2[j];
        #pragma unroll
        for (int k = 0; k < Hh; ++k) {
            w1[k]  = W_hh1[j * Hh + k];
            wi2[k] = W_ih2[j * Hh + k];
            wh2[k] = W_hh2[j * Hh + k];
        }
    }

    const int wv = tid >> 6;               // wave id 0..3
    const int ln = tid & 63;               // lane
    const float wlin_l = (ln < Hh) ? W_lin[ln] : 0.0f;
    const float blin   = b_lin[0];

    __syncthreads();

    for (int s = 0; s < S; ++s) {
        // ======== G1: gates1[j] = b1 + xin*W_ih1[j] + h1·W_hh1[j] ========
        if (j < G4) {
            float xin = (s < T) ? x_lds[s] : o_lds;
            float a0 = b1_j + xin * wih1_j, a1 = 0.0f, a2 = 0.0f, a3 = 0.0f;
            #pragma unroll
            for (int k = 0; k < 48; k += 4) {
                a0 += w1[k]     * h1[k];
                a1 += w1[k + 1] * h1[k + 1];
                a2 += w1[k + 2] * h1[k + 2];
                a3 += w1[k + 3] * h1[k + 3];
            }
            a0 += w1[48] * h1[48];
            a1 += w1[49] * h1[49];
            g1[j] = (a0 + a2) + (a1 + a3);
        }
        __syncthreads();   // B1: g1 complete

        // ======== U1: wave0 lanes<50 update layer-1 state ========
        if (wv == 0 && ln < Hh) {
            float ig = g1[ln], fg = g1[ln + Hh], gg = g1[ln + 2 * Hh], og = g1[ln + 3 * Hh];
            float c  = c1v[ln];
            float cn = fast_sigmoid(fg) * c + fast_sigmoid(ig) * fast_tanh(gg);
            c1v[ln] = cn;
            h1[ln]  = fast_sigmoid(og) * fast_tanh(cn);
        }
        __syncthreads();   // B2: h1 complete

        // wave1 preloads c2 for its redundant U2 compute (c2 stable during G2)
        float cp2 = 0.0f;
        if (wv == 1 && ln < Hh) cp2 = c2v[ln];

        // ======== G2: gates2[j] = b2 + h1·W_ih2[j] + h2·W_hh2[j] ========
        if (j < G4) {
            float a0 = b2_j, a1 = 0.0f, a2 = 0.0f, a3 = 0.0f;
            #pragma unroll
            for (int k = 0; k < 48; k += 4) {
                a0 += wi2[k]     * h1[k];
                a1 += wi2[k + 1] * h1[k + 1];
                a2 += wi2[k + 2] * h1[k + 2];
                a3 += wi2[k + 3] * h1[k + 3];
            }
            a0 += wi2[48] * h1[48];
            a1 += wi2[49] * h1[49];
            #pragma unroll
            for (int k = 0; k < 48; k += 4) {
                a0 += wh2[k]     * h2[k];
                a1 += wh2[k + 1] * h2[k + 1];
                a2 += wh2[k + 2] * h2[k + 2];
                a3 += wh2[k + 3] * h2[k + 3];
            }
            a0 += wh2[48] * h2[48];
            a1 += wh2[49] * h2[49];
            g2[j] = (a0 + a2) + (a1 + a3);
        }
        __syncthreads();   // B3: g2 complete

        // ======== U2a: wave0 = layer-2 state update ========
        if (wv == 0 && ln < Hh) {
            float ig = g2[ln], fg = g2[ln + Hh], gg = g2[ln + 2 * Hh], og = g2[ln + 3 * Hh];
            float c  = c2v[ln];
            float cn = fast_sigmoid(fg) * c + fast_sigmoid(ig) * fast_tanh(gg);
            c2v[ln] = cn;
            h2[ln]  = fast_sigmoid(og) * fast_tanh(cn);
        }
        // ======== U2b: wave1 = output dot (redundant activations) ========
        if (wv == 1) {
            float part = 0.0f;
            if (ln < Hh) {
                float ig = g2[ln], fg = g2[ln + Hh], gg = g2[ln + 2 * Hh], og = g2[ln + 3 * Hh];
                float cn = fast_sigmoid(fg) * cp2 + fast_sigmoid(ig) * fast_tanh(gg);
                float hn = fast_sigmoid(og) * fast_tanh(cn);
                part = hn * wlin_l;
            }
            #pragma unroll
            for (int off = 32; off > 0; off >>= 1)
                part += __shfl_down(part, off);
            if (ln == 0) {
                float o = part + blin;
                out[(size_t)b * S + s] = o;
                o_lds = o;
            }
        }
        // B4 only needed once o_lds feeds the next step's G1 (predict phase)
        if (s >= T - 1) __syncthreads();
        // else: no barrier. Hazard check: g1(s+1) writes race nothing (all
        // waves passed B3 > B2 > U1's g1 reads); g2(s+1) writes happen after
        // B2(s+1), which follows wave0/1's U2(s) g2 reads; h2/c2 writes by
        // wave0 are visible to G2(s+1) readers via B1(s+1)+B2(s+1).
    }
}

extern "C" void kernel_launch(void* const* d_in, const int* in_sizes, int n_in,
                              void* d_out, int out_size, void* d_ws, size_t ws_size,
                              hipStream_t stream) {
    const float* x      = (const float*)d_in[0];
    const float* W_ih1  = (const float*)d_in[1];
    const float* W_hh1  = (const float*)d_in[2];
    const float* b_ih1  = (const float*)d_in[3];
    const float* b_hh1  = (const float*)d_in[4];
    const float* W_ih2  = (const float*)d_in[5];
    const float* W_hh2  = (const float*)d_in[6];
    const float* b_ih2  = (const float*)d_in[7];
    const float* b_hh2  = (const float*)d_in[8];
    const float* W_lin  = (const float*)d_in[9];
    const float* b_lin  = (const float*)d_in[10];
    const int*   pred   = (const int*)d_in[11];
    float* out = (float*)d_out;

    const int B = 512;                 // fixed by setup_inputs
    const int T = in_sizes[0] / B;     // 1024

    dim3 grid(B), block(256);
    hipLaunchKernelGGL(sine_lstm_kernel, grid, block, 0, stream,
                       x, W_ih1, W_hh1, b_ih1, b_hh1,
                       W_ih2, W_hh2, b_ih2, b_hh2,
                       W_lin, b_lin, pred, out, T);
}